// Round 2
// baseline (2063.408 us; speedup 1.0000x reference)
//
#include <hip/hip_runtime.h>
#include <math.h>

// Problem constants
#define BS_ 4
#define N_  2048
#define D_  1024
#define H_  8
#define DH_ 128

typedef __attribute__((ext_vector_type(8))) short short8;
typedef __attribute__((ext_vector_type(4))) short short4_t;
typedef __attribute__((ext_vector_type(4))) float float4_t;

__device__ __forceinline__ unsigned short f2bf(float f) {
    union { float f; unsigned u; } v; v.f = f;
    unsigned r = v.u + 0x7FFFu + ((v.u >> 16) & 1u);   // RNE
    return (unsigned short)(r >> 16);
}
__device__ __forceinline__ float bf2f(unsigned short h) {
    union { unsigned u; float f; } v; v.u = ((unsigned)h) << 16;
    return v.f;
}
// split fp32 -> (hi, lo) bf16 pair; hi+lo reproduces x to ~2^-18 rel
__device__ __forceinline__ void split4(float a, float b, float c, float d,
                                       short4_t* hi, short4_t* lo) {
    unsigned short h0 = f2bf(a), h1 = f2bf(b), h2 = f2bf(c), h3 = f2bf(d);
    (*hi)[0] = (short)h0; (*hi)[1] = (short)h1; (*hi)[2] = (short)h2; (*hi)[3] = (short)h3;
    (*lo)[0] = (short)f2bf(a - bf2f(h0));
    (*lo)[1] = (short)f2bf(b - bf2f(h1));
    (*lo)[2] = (short)f2bf(c - bf2f(h2));
    (*lo)[3] = (short)f2bf(d - bf2f(h3));
}

// ---------------------------------------------------------------------------
// Kernel 1: AP[p,2u]=sin(p/10000^(2u/1024)), AP[p,2u+1]=cos(...). fp32 table.
// ---------------------------------------------------------------------------
__global__ void ap_kernel(float* __restrict__ AP) {
    int idx = blockIdx.x * blockDim.x + threadIdx.x;   // 2,097,152 = 2048*1024
    int p = idx >> 10, u = idx & 1023;
    double sc = pow(10000.0, ((double)(2 * u)) / 1024.0);
    float angle = (float)p / (float)sc;
    float2 v = make_float2(sinf(angle), cosf(angle));
    *reinterpret_cast<float2*>(AP + (size_t)p * N_ + 2 * u) = v;
}

// ---------------------------------------------------------------------------
// Kernel 2: QKV projections from fp32 x,W.  Q,K: split-bf16 3-term MFMA,
// stored as (hi,lo) bf16 pairs.  V: plain bf16 (hi-only), stored transposed.
// Block tile 128(q) x 128(e), BK=32.  LDS row = [hi(32) | lo(32)] pad->72.
// ---------------------------------------------------------------------------
__global__ __launch_bounds__(256, 4) void qkv_kernel(
    const float* __restrict__ x,
    const float* __restrict__ Wq,
    const float* __restrict__ Wk,
    const float* __restrict__ Wv,
    unsigned short* __restrict__ Qhi, unsigned short* __restrict__ Qlo,
    unsigned short* __restrict__ Khi, unsigned short* __restrict__ Klo,
    unsigned short* __restrict__ VTo)
{
    const int qt  = blockIdx.x;           // 16 q-tiles
    const int mat = blockIdx.y;           // 0=Q 1=K 2=V
    const int bh  = blockIdx.z;           // 32
    const int b = bh >> 3, h = bh & 7;
    const int tid = threadIdx.x;
    const int wave = tid >> 6, lane = tid & 63;
    const int quad = lane >> 4, l16 = lane & 15;

    __shared__ short ldsX[128 * 72];
    __shared__ short ldsW[128 * 72];

    const float* W  = (mat == 0 ? Wq : (mat == 1 ? Wk : Wv)) + (size_t)h * DH_ * D_;
    const float* Xg = x + ((size_t)b * N_ + (size_t)qt * 128) * D_;
    const bool vmode = (mat == 2);

    float4_t acc[2][8];
#pragma unroll
    for (int i = 0; i < 2; ++i)
#pragma unroll
        for (int j = 0; j < 8; ++j) acc[i][j] = (float4_t)(0.f);

    for (int kt = 0; kt < 32; ++kt) {
        __syncthreads();
        for (int c = tid; c < 1024; c += 256) {        // 128 rows x 8 float4
            int row = c >> 3, s4 = c & 7;
            float4 xv = *(const float4*)(Xg + (size_t)row * D_ + kt * 32 + s4 * 4);
            short4_t hi, lo;
            split4(xv.x, xv.y, xv.z, xv.w, &hi, &lo);
            *(short4_t*)(ldsX + row * 72 + s4 * 4) = hi;
            *(short4_t*)(ldsX + row * 72 + 32 + s4 * 4) = lo;
            float4 wv = *(const float4*)(W + (size_t)row * D_ + kt * 32 + s4 * 4);
            split4(wv.x, wv.y, wv.z, wv.w, &hi, &lo);
            *(short4_t*)(ldsW + row * 72 + s4 * 4) = hi;
            *(short4_t*)(ldsW + row * 72 + 32 + s4 * 4) = lo;
        }
        __syncthreads();
        if (vmode) {
            // C[e,q]: A = Whi rows(e), B = Xhi rows(q); hi-only
            short8 afr[2];
#pragma unroll
            for (int mi = 0; mi < 2; ++mi)
                afr[mi] = *(const short8*)(ldsW + (wave * 32 + mi * 16 + l16) * 72 + quad * 8);
#pragma unroll
            for (int ne = 0; ne < 8; ++ne) {
                short8 bfr = *(const short8*)(ldsX + (ne * 16 + l16) * 72 + quad * 8);
#pragma unroll
                for (int mi = 0; mi < 2; ++mi)
                    acc[mi][ne] = __builtin_amdgcn_mfma_f32_16x16x32_bf16(afr[mi], bfr, acc[mi][ne], 0, 0, 0);
            }
        } else {
            // 3-term split: hi*hi, hi*lo, lo*hi (t-major chain)
#pragma unroll
            for (int t = 0; t < 3; ++t) {
                const int ab = (t == 2) ? 32 : 0;
                const int bb = (t == 1) ? 32 : 0;
                short8 afr[2];
#pragma unroll
                for (int mi = 0; mi < 2; ++mi)
                    afr[mi] = *(const short8*)(ldsX + (wave * 32 + mi * 16 + l16) * 72 + ab + quad * 8);
#pragma unroll
                for (int ne = 0; ne < 8; ++ne) {
                    short8 bfr = *(const short8*)(ldsW + (ne * 16 + l16) * 72 + bb + quad * 8);
#pragma unroll
                    for (int mi = 0; mi < 2; ++mi)
                        acc[mi][ne] = __builtin_amdgcn_mfma_f32_16x16x32_bf16(afr[mi], bfr, acc[mi][ne], 0, 0, 0);
                }
            }
        }
    }

    if (!vmode) {
        unsigned short* Hi = (mat == 0) ? Qhi : Khi;
        unsigned short* Lo = (mat == 0) ? Qlo : Klo;
        const size_t base = (size_t)bh * N_ * DH_ + (size_t)qt * 128 * DH_;
#pragma unroll
        for (int mi = 0; mi < 2; ++mi)
#pragma unroll
            for (int ne = 0; ne < 8; ++ne)
#pragma unroll
                for (int r = 0; r < 4; ++r) {
                    int row = wave * 32 + mi * 16 + quad * 4 + r;     // q
                    int col = ne * 16 + l16;                          // e
                    float q = acc[mi][ne][r];
                    unsigned short hv = f2bf(q);
                    unsigned short lv = f2bf(q - bf2f(hv));
                    Hi[base + (size_t)row * DH_ + col] = hv;
                    Lo[base + (size_t)row * DH_ + col] = lv;
                }
    } else {
        unsigned short* Cg = VTo + (size_t)bh * DH_ * N_;
#pragma unroll
        for (int mi = 0; mi < 2; ++mi)
#pragma unroll
            for (int ne = 0; ne < 8; ++ne)
#pragma unroll
                for (int r = 0; r < 4; ++r) {
                    int e = wave * 32 + mi * 16 + quad * 4 + r;       // e rows
                    int q = qt * 128 + ne * 16 + l16;                 // q cols
                    Cg[(size_t)e * N_ + q] = f2bf(acc[mi][ne][r]);
                }
    }
}

// ---------------------------------------------------------------------------
// Kernel 3 (pass A): per-row softmax stats m_j, l_j over full key axis.
// Block: 64 j-rows resident (split Q), stream 32 k-tiles of 64 (split K).
// LDS row = [hi(128) | lo(128)] pad->264 shorts (528B, 16B-aligned).
// Wave w owns j-subtile w*16; 12-chunk split-MFMA chain (t-major, kc-minor)
// MUST match attn_kernel exactly (bitwise-identical E => exp(e-m) <= 1).
// ---------------------------------------------------------------------------
__global__ __launch_bounds__(256, 2) void rowstats_kernel(
    const unsigned short* __restrict__ Qhi, const unsigned short* __restrict__ Qlo,
    const unsigned short* __restrict__ Khi, const unsigned short* __restrict__ Klo,
    const float* __restrict__ AP,
    const int* __restrict__ mask,
    float* __restrict__ mrow, float* __restrict__ lrow)
{
    const int jt = blockIdx.x;    // 32 j-tiles of 64
    const int bh = blockIdx.y;    // 32
    const int b = bh >> 3;
    const int tid = threadIdx.x, wave = tid >> 6, lane = tid & 63;
    const int quad = lane >> 4, l16 = lane & 15;

    __shared__ short ldsQ[64 * 264];
    __shared__ short ldsK[64 * 264];
    __shared__ int   s_mk[64];

    const size_t Qbase = ((size_t)bh * N_ + (size_t)jt * 64) * DH_;
    for (int c = tid; c < 1024; c += 256) {
        int row = c >> 4, seg = c & 15;
        *(short8*)(ldsQ + row * 264 + seg * 8) =
            *(const short8*)(Qhi + Qbase + (size_t)row * DH_ + seg * 8);
        *(short8*)(ldsQ + row * 264 + 128 + seg * 8) =
            *(const short8*)(Qlo + Qbase + (size_t)row * DH_ + seg * 8);
    }

    float m_run[4], l_run[4];
    int mj_on[4];
#pragma unroll
    for (int r = 0; r < 4; ++r) {
        m_run[r] = -3.0e38f; l_run[r] = 0.f;
        int j = jt * 64 + wave * 16 + quad * 4 + r;
        mj_on[r] = mask[b * N_ + j];
    }

    for (int kt = 0; kt < 32; ++kt) {
        __syncthreads();
        const size_t Kbase = ((size_t)bh * N_ + (size_t)kt * 64) * DH_;
        for (int c = tid; c < 1024; c += 256) {
            int row = c >> 4, seg = c & 15;
            *(short8*)(ldsK + row * 264 + seg * 8) =
                *(const short8*)(Khi + Kbase + (size_t)row * DH_ + seg * 8);
            *(short8*)(ldsK + row * 264 + 128 + seg * 8) =
                *(const short8*)(Klo + Kbase + (size_t)row * DH_ + seg * 8);
        }
        if (tid < 64) s_mk[tid] = mask[b * N_ + kt * 64 + tid];
        __syncthreads();

        float4_t acc[4];
#pragma unroll
        for (int nk = 0; nk < 4; ++nk) acc[nk] = (float4_t)(0.f);
#pragma unroll
        for (int t = 0; t < 3; ++t) {
            const int ab = (t == 2) ? 128 : 0;
            const int bb = (t == 1) ? 128 : 0;
#pragma unroll
            for (int kc = 0; kc < 4; ++kc) {
                short8 afr = *(const short8*)(ldsQ + (wave * 16 + l16) * 264 + ab + kc * 32 + quad * 8);
#pragma unroll
                for (int nk = 0; nk < 4; ++nk) {
                    short8 bfr = *(const short8*)(ldsK + (nk * 16 + l16) * 264 + bb + kc * 32 + quad * 8);
                    acc[nk] = __builtin_amdgcn_mfma_f32_16x16x32_bf16(afr, bfr, acc[nk], 0, 0, 0);
                }
            }
        }

        int mk[4];
#pragma unroll
        for (int nk = 0; nk < 4; ++nk) mk[nk] = s_mk[nk * 16 + l16];

#pragma unroll
        for (int r = 0; r < 4; ++r) {
            int j = jt * 64 + wave * 16 + quad * 4 + r;
            const float* APr = AP + (size_t)j * N_ + kt * 64;
            float ev[4];
            float tmax = -3.0e38f;
            int on = mj_on[r];
#pragma unroll
            for (int nk = 0; nk < 4; ++nk) {
                float e = acc[nk][r] + APr[nk * 16 + l16];
                e = (on && mk[nk]) ? e : -1.0e9f;
                ev[nk] = e;
                tmax = fmaxf(tmax, e);
            }
            for (int off = 1; off < 16; off <<= 1)
                tmax = fmaxf(tmax, __shfl_xor(tmax, off, 64));
            float Mn = fmaxf(m_run[r], tmax);
            float s = 0.f;
#pragma unroll
            for (int nk = 0; nk < 4; ++nk) s += __expf(ev[nk] - Mn);
            for (int off = 1; off < 16; off <<= 1)
                s += __shfl_xor(s, off, 64);
            l_run[r] = l_run[r] * __expf(m_run[r] - Mn) + s;
            m_run[r] = Mn;
        }
    }

    if (l16 == 0) {
#pragma unroll
        for (int r = 0; r < 4; ++r) {
            int j = jt * 64 + wave * 16 + quad * 4 + r;
            mrow[(size_t)bh * N_ + j] = m_run[r];
            lrow[(size_t)bh * N_ + j] = l_run[r];
        }
    }
}

// ---------------------------------------------------------------------------
// Kernel 4 (pass B): y[i,e] = sum_j A[j,i] V[j,e], A = exp(E-m_j)/l_j.
// 512 threads (8 waves), K-tile (128 i, split) resident; stream 32 j-tiles
// of 64 (split Q + bf16 V^T).  MFMA1 split chain identical to rowstats.
// A^T round-trips LDS (D-layout -> A-operand layout).  h==7: A -> d_out fp32.
// ---------------------------------------------------------------------------
__global__ __launch_bounds__(512, 2) void attn_kernel(
    const unsigned short* __restrict__ Qhi, const unsigned short* __restrict__ Qlo,
    const unsigned short* __restrict__ Khi, const unsigned short* __restrict__ Klo,
    const unsigned short* __restrict__ VT,
    const float* __restrict__ AP,
    const int* __restrict__ mask,
    const float* __restrict__ mrow,
    const float* __restrict__ lrow,
    unsigned short* __restrict__ yout,    // [BS,N,D] bf16 (ws)
    float* __restrict__ aout)             // [BS,N,N] fp32 (d_out tail)
{
    const int it = blockIdx.x;   // 16 i-tiles (keys)
    const int bh = blockIdx.y;   // 32
    const int b = bh >> 3, h = bh & 7;
    const int tid = threadIdx.x, wave = tid >> 6, lane = tid & 63;  // 8 waves
    const int quad = lane >> 4, l16 = lane & 15;

    __shared__ short ldsK[128 * 264];   // K_i split, resident   (67.6 KB)
    __shared__ short ldsQ[64 * 264];    // Q_j split, streamed   (33.8 KB)
    __shared__ short ldsA[128 * 72];    // A^T [i][j] bf16       (18.4 KB)
    __shared__ short ldsV[128 * 72];    // V^T [e][j] bf16       (18.4 KB)
    __shared__ float s_m[64];
    __shared__ float s_il[64];
    __shared__ int   s_mj[64];

    const size_t Kbase = ((size_t)bh * N_ + (size_t)it * 128) * DH_;
    for (int c = tid; c < 2048; c += 512) {
        int row = c >> 4, seg = c & 15;
        *(short8*)(ldsK + row * 264 + seg * 8) =
            *(const short8*)(Khi + Kbase + (size_t)row * DH_ + seg * 8);
        *(short8*)(ldsK + row * 264 + 128 + seg * 8) =
            *(const short8*)(Klo + Kbase + (size_t)row * DH_ + seg * 8);
    }

    const int i_local = wave * 16 + l16;
    const int ig = it * 128 + i_local;
    const int ion = mask[b * N_ + ig];

    float4_t accy[8];
#pragma unroll
    for (int ne = 0; ne < 8; ++ne) accy[ne] = (float4_t)(0.f);

    const bool do_aout = (h == 7);

    for (int jt = 0; jt < 32; ++jt) {
        const int j0 = jt * 64;
        __syncthreads();   // prior MFMA2 reads (ldsA/ldsV) done; K staged at jt==0

        const size_t Qbase = ((size_t)bh * N_ + j0) * DH_;
        for (int c = tid; c < 1024; c += 512) {
            int row = c >> 4, seg = c & 15;
            *(short8*)(ldsQ + row * 264 + seg * 8) =
                *(const short8*)(Qhi + Qbase + (size_t)row * DH_ + seg * 8);
            *(short8*)(ldsQ + row * 264 + 128 + seg * 8) =
                *(const short8*)(Qlo + Qbase + (size_t)row * DH_ + seg * 8);
        }
        const unsigned short* Vg = VT + (size_t)bh * DH_ * N_ + j0;
        for (int c = tid; c < 1024; c += 512) {
            int e = c >> 3, seg = c & 7;
            *(short8*)(ldsV + e * 72 + seg * 8) =
                *(const short8*)(Vg + (size_t)e * N_ + seg * 8);
        }
        if (tid < 64) {
            int j = j0 + tid;
            s_m[tid]  = mrow[(size_t)bh * N_ + j];
            s_il[tid] = 1.0f / lrow[(size_t)bh * N_ + j];
            s_mj[tid] = mask[b * N_ + j];
        }
        __syncthreads();

        // MFMA1: S[j(64), i(16 per wave)] — split chain matches rowstats
        float4_t accs[4];
#pragma unroll
        for (int mj = 0; mj < 4; ++mj) accs[mj] = (float4_t)(0.f);
#pragma unroll
        for (int t = 0; t < 3; ++t) {
            const int ab = (t == 2) ? 128 : 0;
            const int bb = (t == 1) ? 128 : 0;
#pragma unroll
            for (int kc = 0; kc < 4; ++kc) {
                short8 bfr = *(const short8*)(ldsK + (wave * 16 + l16) * 264 + bb + kc * 32 + quad * 8);
#pragma unroll
                for (int mj = 0; mj < 4; ++mj) {
                    short8 afr = *(const short8*)(ldsQ + (mj * 16 + l16) * 264 + ab + kc * 32 + quad * 8);
                    accs[mj] = __builtin_amdgcn_mfma_f32_16x16x32_bf16(afr, bfr, accs[mj], 0, 0, 0);
                }
            }
        }

        // A = exp(E - m_j)/l_j ; write A^T to LDS (bf16); h==7: fp32 -> d_out
#pragma unroll
        for (int mj = 0; mj < 4; ++mj) {
            short4_t pk;
#pragma unroll
            for (int r = 0; r < 4; ++r) {
                int jl = mj * 16 + quad * 4 + r;
                int j = j0 + jl;
                float e = accs[mj][r] + AP[(size_t)j * N_ + ig];
                e = (s_mj[jl] && ion) ? e : -1.0e9f;
                float a = __expf(e - s_m[jl]) * s_il[jl];
                pk[r] = (short)f2bf(a);
                if (do_aout)
                    aout[((size_t)(b * N_ + j)) * N_ + ig] = a;
            }
            *(short4_t*)(ldsA + (size_t)i_local * 72 + mj * 16 + quad * 4) = pk;
        }
        __syncthreads();

        // MFMA2: y[i(16 per wave), e(128)] += A^T · V
#pragma unroll
        for (int kcj = 0; kcj < 2; ++kcj) {
            short8 afr = *(const short8*)(ldsA + (wave * 16 + l16) * 72 + kcj * 32 + quad * 8);
#pragma unroll
            for (int ne = 0; ne < 8; ++ne) {
                short8 bfr = *(const short8*)(ldsV + (ne * 16 + l16) * 72 + kcj * 32 + quad * 8);
                accy[ne] = __builtin_amdgcn_mfma_f32_16x16x32_bf16(afr, bfr, accy[ne], 0, 0, 0);
            }
        }
    }

    // store y[b, i, h*128+e] as bf16
#pragma unroll
    for (int ne = 0; ne < 8; ++ne)
#pragma unroll
        for (int r = 0; r < 4; ++r) {
            int irow = wave * 16 + quad * 4 + r;
            int e = ne * 16 + l16;
            yout[((size_t)b * N_ + it * 128 + irow) * D_ + h * DH_ + e] =
                f2bf(accy[ne][r]);
        }
}

// ---------------------------------------------------------------------------
// Kernel 5: out[m,o] = sum_d y[m,d] Wout[o,d]  (y bf16, Wout fp32->bf16,
// out fp32).  NT GEMM, M=8192, N=1024, K=1024.
// ---------------------------------------------------------------------------
__global__ __launch_bounds__(256, 4) void outgemm_kernel(
    const unsigned short* __restrict__ A,     // y  [8192][1024] bf16
    const float* __restrict__ B,              // Wout [1024][1024] fp32
    float* __restrict__ C)                    // out [8192][1024] fp32
{
    const int nt = blockIdx.x;   // 8
    const int mt = blockIdx.y;   // 64
    const int tid = threadIdx.x, wave = tid >> 6, lane = tid & 63;
    const int quad = lane >> 4, l16 = lane & 15;

    __shared__ short ldsA[128 * 40];
    __shared__ short ldsB[128 * 40];

    const unsigned short* Ag = A + (size_t)mt * 128 * D_;
    const float* Bg = B + (size_t)nt * 128 * D_;

    float4_t acc[2][8];
#pragma unroll
    for (int i = 0; i < 2; ++i)
#pragma unroll
        for (int j = 0; j < 8; ++j) acc[i][j] = (float4_t)(0.f);

    for (int kt = 0; kt < 32; ++kt) {
        __syncthreads();
        for (int c = tid; c < 512; c += 256) {
            int row = c >> 2, seg = c & 3;
            *(short8*)(ldsA + row * 40 + seg * 8) =
                *(const short8*)(Ag + (size_t)row * D_ + kt * 32 + seg * 8);
        }
        for (int c = tid; c < 1024; c += 256) {
            int row = c >> 3, s4 = c & 7;
            float4 wv = *(const float4*)(Bg + (size_t)row * D_ + kt * 32 + s4 * 4);
            short4_t h4;
            h4[0] = (short)f2bf(wv.x); h4[1] = (short)f2bf(wv.y);
            h4[2] = (short)f2bf(wv.z); h4[3] = (short)f2bf(wv.w);
            *(short4_t*)(ldsB + row * 40 + s4 * 4) = h4;
        }
        __syncthreads();
        short8 afr[2];
#pragma unroll
        for (int mi = 0; mi < 2; ++mi)
            afr[mi] = *(const short8*)(ldsA + (wave * 32 + mi * 16 + l16) * 40 + quad * 8);
#pragma unroll
        for (int ne = 0; ne < 8; ++ne) {
            short8 bfr = *(const short8*)(ldsB + (ne * 16 + l16) * 40 + quad * 8);
#pragma unroll
            for (int mi = 0; mi < 2; ++mi)
                acc[mi][ne] = __builtin_amdgcn_mfma_f32_16x16x32_bf16(afr[mi], bfr, acc[mi][ne], 0, 0, 0);
        }
    }

#pragma unroll
    for (int mi = 0; mi < 2; ++mi)
#pragma unroll
        for (int ne = 0; ne < 8; ++ne)
#pragma unroll
            for (int r = 0; r < 4; ++r) {
                int row = mt * 128 + wave * 32 + mi * 16 + quad * 4 + r;
                int col = nt * 128 + ne * 16 + l16;
                C[(size_t)row * D_ + col] = acc[mi][ne][r];
            }
}

// ---------------------------------------------------------------------------
extern "C" void kernel_launch(void* const* d_in, const int* in_sizes, int n_in,
                              void* d_out, int out_size, void* d_ws, size_t ws_size,
                              hipStream_t stream)
{
    const float* x   = (const float*)d_in[0];
    const int*   msk = (const int*)d_in[1];
    const float* Wq  = (const float*)d_in[2];
    const float* Wk  = (const float*)d_in[3];
    const float* Wv  = (const float*)d_in[4];
    const float* Wo  = (const float*)d_in[5];

    float* out  = (float*)d_out;                         // [4,2048,1024] fp32
    float* aout = out + (size_t)BS_ * N_ * D_;           // [4,2048,2048] fp32

    // workspace layout (~118 MB)
    char* w = (char*)d_ws;
    float* AP = (float*)w;                    w += (size_t)N_ * N_ * 4;
    const size_t szqk = (size_t)BS_ * H_ * N_ * DH_ * 2;       // bf16 bytes
    unsigned short* Qhi = (unsigned short*)w; w += szqk;
    unsigned short* Qlo = (unsigned short*)w; w += szqk;
    unsigned short* Khi = (unsigned short*)w; w += szqk;
    unsigned short* Klo = (unsigned short*)w; w += szqk;
    unsigned short* VT  = (unsigned short*)w; w += szqk;
    float* mrow = (float*)w;                  w += (size_t)BS_ * H_ * N_ * 4;
    float* lrow = (float*)w;                  w += (size_t)BS_ * H_ * N_ * 4;
    unsigned short* yb = (unsigned short*)w;  w += (size_t)BS_ * N_ * D_ * 2;

    ap_kernel<<<8192, 256, 0, stream>>>(AP);
    qkv_kernel<<<dim3(16, 3, 32), 256, 0, stream>>>(x, Wq, Wk, Wv, Qhi, Qlo, Khi, Klo, VT);
    rowstats_kernel<<<dim3(32, 32), 256, 0, stream>>>(Qhi, Qlo, Khi, Klo, AP, msk, mrow, lrow);
    attn_kernel<<<dim3(16, 32), 512, 0, stream>>>(Qhi, Qlo, Khi, Klo, VT, AP, msk, mrow, lrow, yb, aout);
    outgemm_kernel<<<dim3(8, 64), 256, 0, stream>>>(yb, Wo, out);
}

// Round 4
// 1013.575 us; speedup vs baseline: 2.0358x; 2.0358x over previous
//
#include <hip/hip_runtime.h>
#include <math.h>

// Problem constants
#define BS_ 4
#define N_  2048
#define D_  1024
#define H_  8
#define DH_ 128

typedef __attribute__((ext_vector_type(8))) short short8;
typedef __attribute__((ext_vector_type(4))) short short4_t;
typedef __attribute__((ext_vector_type(4))) float float4_t;
typedef unsigned short u16;

__device__ __forceinline__ u16 f2bf(float f) {
    union { float f; unsigned u; } v; v.f = f;
    unsigned r = v.u + 0x7FFFu + ((v.u >> 16) & 1u);   // RNE
    return (u16)(r >> 16);
}
__device__ __forceinline__ float bf2f(u16 h) {
    union { unsigned u; float f; } v; v.u = ((unsigned)h) << 16;
    return v.f;
}
__device__ __forceinline__ void split4(float a, float b, float c, float d,
                                       short4_t* hi, short4_t* lo) {
    u16 h0 = f2bf(a), h1 = f2bf(b), h2 = f2bf(c), h3 = f2bf(d);
    (*hi)[0] = (short)h0; (*hi)[1] = (short)h1; (*hi)[2] = (short)h2; (*hi)[3] = (short)h3;
    (*lo)[0] = (short)f2bf(a - bf2f(h0));
    (*lo)[1] = (short)f2bf(b - bf2f(h1));
    (*lo)[2] = (short)f2bf(c - bf2f(h2));
    (*lo)[3] = (short)f2bf(d - bf2f(h3));
}

// async global->LDS, 16B per lane; LDS dest = wave-uniform base + lane*16.
// C-style casts = addrspacecast (reinterpret_cast across AS is ill-formed).
__device__ __forceinline__ void gl_lds16(const void* g, void* l) {
    __builtin_amdgcn_global_load_lds(
        (const __attribute__((address_space(1))) unsigned int*)g,
        (__attribute__((address_space(3))) unsigned int*)l,
        16, 0, 0);
}

// ---------------------------------------------------------------------------
// Kernel 1: AP table, bf16.  AP[p,2u]=sin(p/10000^(2u/1024)), AP[p,2u+1]=cos.
// ---------------------------------------------------------------------------
__global__ void ap_kernel(unsigned int* __restrict__ APb) {
    int idx = blockIdx.x * blockDim.x + threadIdx.x;   // 2,097,152 = 2048*1024
    int p = idx >> 10, u = idx & 1023;
    double sc = pow(10000.0, ((double)(2 * u)) / 1024.0);
    float angle = (float)p / (float)sc;
    unsigned pack = (unsigned)f2bf(sinf(angle)) | ((unsigned)f2bf(cosf(angle)) << 16);
    APb[(size_t)p * (N_ / 2) + u] = pack;   // shorts at p*2048 + 2u
}

// ---------------------------------------------------------------------------
// Kernel 2: fp32 -> bf16 hi/lo pre-split of X, Wq|Wk (cat), Wv (hi), Wout (hi).
// All region boundaries are block-aligned (no divergence).
// ---------------------------------------------------------------------------
__global__ void split_kernel(const float* __restrict__ x,
                             const float* __restrict__ Wq, const float* __restrict__ Wk,
                             const float* __restrict__ Wv, const float* __restrict__ Wo,
                             u16* __restrict__ Xhi, u16* __restrict__ Xlo,
                             u16* __restrict__ Whi, u16* __restrict__ Wlo,
                             u16* __restrict__ Wvhi, u16* __restrict__ Wohi) {
    int i = blockIdx.x * 256 + threadIdx.x;            // 3,145,728 float4s
    const float* src; u16 *dhi, *dlo; size_t off;
    if (i < 2097152)      { src = x  + 4*(size_t)i;             dhi = Xhi;  dlo = Xlo;  off = 4*(size_t)i; }
    else if (i < 2359296) { size_t j = i - 2097152; src = Wq + 4*j; dhi = Whi; dlo = Wlo; off = 4*j; }
    else if (i < 2621440) { size_t j = i - 2359296; src = Wk + 4*j; dhi = Whi; dlo = Wlo; off = 1048576 + 4*j; }
    else if (i < 2883584) { size_t j = i - 2621440; src = Wv + 4*j; dhi = Wvhi; dlo = nullptr; off = 4*j; }
    else                  { size_t j = i - 2883584; src = Wo + 4*j; dhi = Wohi; dlo = nullptr; off = 4*j; }
    float4 v = *(const float4*)src;
    short4_t hi, lo;
    split4(v.x, v.y, v.z, v.w, &hi, &lo);
    *(short4_t*)(dhi + off) = hi;
    if (dlo) *(short4_t*)(dlo + off) = lo;
}

// ---------------------------------------------------------------------------
// Kernel 3: Q,K projections.  C[q,n] = sum_d X[q,d] W[n,d], 3-term bf16 split.
// m97 structure: 128x128 tile, BK=32, global_load_lds width 16, no LDS pad
// (64 B rows -> 2-way banks, free).  nt<8 => Q head nt, else K head nt-8.
// ---------------------------------------------------------------------------
__global__ __launch_bounds__(256, 4) void qk_gemm(
    const u16* __restrict__ Xhi, const u16* __restrict__ Xlo,
    const u16* __restrict__ Whi, const u16* __restrict__ Wlo,
    u16* __restrict__ Qhi, u16* __restrict__ Qlo,
    u16* __restrict__ Khi, u16* __restrict__ Klo)
{
    const int mt = blockIdx.x;   // 64 (q-tiles over BS*N)
    const int nt = blockIdx.y;   // 16 (Q heads 0..7, K heads 8..15)
    const int tid = threadIdx.x, wave = tid >> 6, lane = tid & 63;
    const int quad = lane >> 4, l16 = lane & 15;

    __shared__ __align__(16) u16 sA[2][128 * 32];
    __shared__ __align__(16) u16 sB[2][128 * 32];

    const int srow = lane >> 2;          // 16 rows per wave instruction
    const int scol = (lane & 3) * 8;     // 4 chunks of 8 shorts per 32-col row
    const size_t aoff = ((size_t)(mt * 128) + srow) * 1024 + scol;
    const size_t boff = ((size_t)(nt * 128) + srow) * 1024 + scol;
    const int r0 = wave * 16, r1 = 64 + wave * 16;

    float4_t acc[2][8];
#pragma unroll
    for (int i = 0; i < 2; ++i)
#pragma unroll
        for (int j = 0; j < 8; ++j) acc[i][j] = (float4_t)(0.f);

    for (int kt = 0; kt < 32; ++kt) {
        __syncthreads();
        const int kc0 = kt * 32;
        gl_lds16(Xhi + aoff + (size_t)r0 * 1024 + kc0, &sA[0][r0 * 32]);
        gl_lds16(Xhi + aoff + (size_t)r1 * 1024 + kc0, &sA[0][r1 * 32]);
        gl_lds16(Xlo + aoff + (size_t)r0 * 1024 + kc0, &sA[1][r0 * 32]);
        gl_lds16(Xlo + aoff + (size_t)r1 * 1024 + kc0, &sA[1][r1 * 32]);
        gl_lds16(Whi + boff + (size_t)r0 * 1024 + kc0, &sB[0][r0 * 32]);
        gl_lds16(Whi + boff + (size_t)r1 * 1024 + kc0, &sB[0][r1 * 32]);
        gl_lds16(Wlo + boff + (size_t)r0 * 1024 + kc0, &sB[1][r0 * 32]);
        gl_lds16(Wlo + boff + (size_t)r1 * 1024 + kc0, &sB[1][r1 * 32]);
        __syncthreads();

#pragma unroll
        for (int t = 0; t < 3; ++t) {
            const u16* As = sA[t == 2 ? 1 : 0];
            const u16* Bs = sB[t == 1 ? 1 : 0];
            short8 afr[2];
#pragma unroll
            for (int mi = 0; mi < 2; ++mi)
                afr[mi] = *(const short8*)(As + (wave * 32 + mi * 16 + l16) * 32 + quad * 8);
#pragma unroll
            for (int ne = 0; ne < 8; ++ne) {
                short8 bfr = *(const short8*)(Bs + (ne * 16 + l16) * 32 + quad * 8);
#pragma unroll
                for (int mi = 0; mi < 2; ++mi)
                    acc[mi][ne] = __builtin_amdgcn_mfma_f32_16x16x32_bf16(afr[mi], bfr, acc[mi][ne], 0, 0, 0);
            }
        }
    }

    const int b = mt >> 4, q0 = (mt & 15) * 128;
    const bool isQ = (nt < 8);
    u16* Hi = isQ ? Qhi : Khi;
    u16* Lo = isQ ? Qlo : Klo;
    const int h = isQ ? nt : nt - 8;
    const size_t base = (size_t)(b * 8 + h) * N_ * DH_;
#pragma unroll
    for (int mi = 0; mi < 2; ++mi)
#pragma unroll
        for (int ne = 0; ne < 8; ++ne)
#pragma unroll
            for (int r = 0; r < 4; ++r) {
                int q = q0 + wave * 32 + mi * 16 + quad * 4 + r;
                int e = ne * 16 + l16;
                float v = acc[mi][ne][r];
                u16 hv = f2bf(v);
                Hi[base + (size_t)q * DH_ + e] = hv;
                Lo[base + (size_t)q * DH_ + e] = f2bf(v - bf2f(hv));
            }
}

// ---------------------------------------------------------------------------
// Kernel 4: V^T[bh][e][q] = sum_d Wv[h*128+e,d] X[b*2048+q,d]  (1-term bf16).
// ---------------------------------------------------------------------------
__global__ __launch_bounds__(256, 4) void v_gemm(
    const u16* __restrict__ Wvhi, const u16* __restrict__ Xhi,
    u16* __restrict__ VT)
{
    const int qt = blockIdx.x;   // 16
    const int bh = blockIdx.y;   // 32
    const int b = bh >> 3, h = bh & 7;
    const int tid = threadIdx.x, wave = tid >> 6, lane = tid & 63;
    const int quad = lane >> 4, l16 = lane & 15;

    __shared__ __align__(16) u16 sA[128 * 32];   // Wv rows (e)
    __shared__ __align__(16) u16 sB[128 * 32];   // X rows (q)

    const int srow = lane >> 2, scol = (lane & 3) * 8;
    const size_t aoff = ((size_t)(h * 128) + srow) * 1024 + scol;
    const size_t boff = ((size_t)(b * N_ + qt * 128) + srow) * 1024 + scol;
    const int r0 = wave * 16, r1 = 64 + wave * 16;

    float4_t acc[2][8];
#pragma unroll
    for (int i = 0; i < 2; ++i)
#pragma unroll
        for (int j = 0; j < 8; ++j) acc[i][j] = (float4_t)(0.f);

    for (int kt = 0; kt < 32; ++kt) {
        __syncthreads();
        const int kc0 = kt * 32;
        gl_lds16(Wvhi + aoff + (size_t)r0 * 1024 + kc0, &sA[r0 * 32]);
        gl_lds16(Wvhi + aoff + (size_t)r1 * 1024 + kc0, &sA[r1 * 32]);
        gl_lds16(Xhi  + boff + (size_t)r0 * 1024 + kc0, &sB[r0 * 32]);
        gl_lds16(Xhi  + boff + (size_t)r1 * 1024 + kc0, &sB[r1 * 32]);
        __syncthreads();

        short8 afr[2];
#pragma unroll
        for (int mi = 0; mi < 2; ++mi)
            afr[mi] = *(const short8*)(sA + (wave * 32 + mi * 16 + l16) * 32 + quad * 8);
#pragma unroll
        for (int ne = 0; ne < 8; ++ne) {
            short8 bfr = *(const short8*)(sB + (ne * 16 + l16) * 32 + quad * 8);
#pragma unroll
            for (int mi = 0; mi < 2; ++mi)
                acc[mi][ne] = __builtin_amdgcn_mfma_f32_16x16x32_bf16(afr[mi], bfr, acc[mi][ne], 0, 0, 0);
        }
    }

    u16* Cg = VT + (size_t)bh * DH_ * N_;
#pragma unroll
    for (int mi = 0; mi < 2; ++mi)
#pragma unroll
        for (int ne = 0; ne < 8; ++ne)
#pragma unroll
            for (int r = 0; r < 4; ++r) {
                int e = wave * 32 + mi * 16 + quad * 4 + r;
                int q = qt * 128 + ne * 16 + l16;
                Cg[(size_t)e * N_ + q] = f2bf(acc[mi][ne][r]);
            }
}

// ---------------------------------------------------------------------------
// Kernel 5 (pass A): l_j = sum_k exp(E[j,k]) directly — no running max.
// exp(E) <= e^~25 (fp32-safe); masked -> exp(-1e9) = 0; dead rows -> l = 0.
// Per-lane partials, ONE shuffle reduce at the end.  MFMA chain (t,kc order)
// bitwise-matches attn_kernel.
// ---------------------------------------------------------------------------
__global__ __launch_bounds__(256, 2) void rowstats_kernel(
    const u16* __restrict__ Qhi, const u16* __restrict__ Qlo,
    const u16* __restrict__ Khi, const u16* __restrict__ Klo,
    const u16* __restrict__ APb,
    const int* __restrict__ mask,
    float* __restrict__ lrow)
{
    const int jt = blockIdx.x;    // 32 j-tiles of 64
    const int bh = blockIdx.y;    // 32
    const int b = bh >> 3;
    const int tid = threadIdx.x, wave = tid >> 6, lane = tid & 63;
    const int quad = lane >> 4, l16 = lane & 15;

    __shared__ __align__(16) u16 ldsQ[64 * 264];
    __shared__ __align__(16) u16 ldsK[64 * 264];
    __shared__ int s_mk[64];

    const size_t Qbase = ((size_t)bh * N_ + (size_t)jt * 64) * DH_;
    for (int c = tid; c < 1024; c += 256) {
        int row = c >> 4, seg = c & 15;
        *(short8*)(ldsQ + row * 264 + seg * 8) =
            *(const short8*)(Qhi + Qbase + (size_t)row * DH_ + seg * 8);
        *(short8*)(ldsQ + row * 264 + 128 + seg * 8) =
            *(const short8*)(Qlo + Qbase + (size_t)row * DH_ + seg * 8);
    }

    float p[4] = {0.f, 0.f, 0.f, 0.f};
    int mj_on[4];
#pragma unroll
    for (int r = 0; r < 4; ++r) {
        int j = jt * 64 + wave * 16 + quad * 4 + r;
        mj_on[r] = mask[b * N_ + j];
    }

    for (int kt = 0; kt < 32; ++kt) {
        __syncthreads();
        const size_t Kbase = ((size_t)bh * N_ + (size_t)kt * 64) * DH_;
        for (int c = tid; c < 1024; c += 256) {
            int row = c >> 4, seg = c & 15;
            *(short8*)(ldsK + row * 264 + seg * 8) =
                *(const short8*)(Khi + Kbase + (size_t)row * DH_ + seg * 8);
            *(short8*)(ldsK + row * 264 + 128 + seg * 8) =
                *(const short8*)(Klo + Kbase + (size_t)row * DH_ + seg * 8);
        }
        if (tid < 64) s_mk[tid] = mask[b * N_ + kt * 64 + tid];
        __syncthreads();

        float4_t acc[4];
#pragma unroll
        for (int nk = 0; nk < 4; ++nk) acc[nk] = (float4_t)(0.f);
#pragma unroll
        for (int t = 0; t < 3; ++t) {
            const int ab = (t == 2) ? 128 : 0;
            const int bb = (t == 1) ? 128 : 0;
#pragma unroll
            for (int kc = 0; kc < 4; ++kc) {
                short8 afr = *(const short8*)(ldsQ + (wave * 16 + l16) * 264 + ab + kc * 32 + quad * 8);
#pragma unroll
                for (int nk = 0; nk < 4; ++nk) {
                    short8 bfr = *(const short8*)(ldsK + (nk * 16 + l16) * 264 + bb + kc * 32 + quad * 8);
                    acc[nk] = __builtin_amdgcn_mfma_f32_16x16x32_bf16(afr, bfr, acc[nk], 0, 0, 0);
                }
            }
        }

        int mk[4];
#pragma unroll
        for (int nk = 0; nk < 4; ++nk) mk[nk] = s_mk[nk * 16 + l16];

#pragma unroll
        for (int r = 0; r < 4; ++r) {
            int j = jt * 64 + wave * 16 + quad * 4 + r;
            const u16* APr = APb + (size_t)j * N_ + kt * 64;
            int on = mj_on[r];
            float s = 0.f;
#pragma unroll
            for (int nk = 0; nk < 4; ++nk) {
                float e = acc[nk][r] + bf2f(APr[nk * 16 + l16]);
                e = (on && mk[nk]) ? e : -1.0e9f;
                s += __expf(e);
            }
            p[r] += s;
        }
    }

#pragma unroll
    for (int r = 0; r < 4; ++r) {
        float s = p[r];
        for (int off = 1; off < 16; off <<= 1)
            s += __shfl_xor(s, off, 64);
        if (l16 == 0) {
            int j = jt * 64 + wave * 16 + quad * 4 + r;
            lrow[(size_t)bh * N_ + j] = s;
        }
    }
}

// ---------------------------------------------------------------------------
// Kernel 6 (pass B): y[i,e] = sum_j A[j,i] V[j,e], A = exp(E)/l_j (dead rows
// -> uniform 1/2048).  512 threads; K_i tile resident; stream j-tiles of 64.
// A^T round-trips LDS.  h==7 stores A (fp32) to d_out.
// ---------------------------------------------------------------------------
__global__ __launch_bounds__(512, 2) void attn_kernel(
    const u16* __restrict__ Qhi, const u16* __restrict__ Qlo,
    const u16* __restrict__ Khi, const u16* __restrict__ Klo,
    const u16* __restrict__ VT,
    const u16* __restrict__ APb,
    const int* __restrict__ mask,
    const float* __restrict__ lrow,
    u16* __restrict__ yout,               // [BS,N,D] bf16 (ws)
    float* __restrict__ aout)             // [BS,N,N] fp32 (d_out tail)
{
    const int it = blockIdx.x;   // 16 i-tiles (keys)
    const int bh = blockIdx.y;   // 32
    const int b = bh >> 3, h = bh & 7;
    const int tid = threadIdx.x, wave = tid >> 6, lane = tid & 63;  // 8 waves
    const int quad = lane >> 4, l16 = lane & 15;

    __shared__ __align__(16) u16 ldsK[128 * 264];   // K_i split, resident
    __shared__ __align__(16) u16 ldsQ[64 * 264];    // Q_j split, streamed
    __shared__ __align__(16) u16 ldsA[128 * 72];    // A^T [i][j] bf16
    __shared__ __align__(16) u16 ldsV[128 * 72];    // V^T [e][j] bf16
    __shared__ float s_il[64];
    __shared__ int   s_dead[64];
    __shared__ int   s_mj[64];

    const size_t Kbase = ((size_t)bh * N_ + (size_t)it * 128) * DH_;
    for (int c = tid; c < 2048; c += 512) {
        int row = c >> 4, seg = c & 15;
        *(short8*)(ldsK + row * 264 + seg * 8) =
            *(const short8*)(Khi + Kbase + (size_t)row * DH_ + seg * 8);
        *(short8*)(ldsK + row * 264 + 128 + seg * 8) =
            *(const short8*)(Klo + Kbase + (size_t)row * DH_ + seg * 8);
    }

    const int i_local = wave * 16 + l16;
    const int ig = it * 128 + i_local;
    const int ion = mask[b * N_ + ig];

    float4_t accy[8];
#pragma unroll
    for (int ne = 0; ne < 8; ++ne) accy[ne] = (float4_t)(0.f);

    const bool do_aout = (h == 7);
    const float inv_n = 1.0f / (float)N_;

    for (int jt = 0; jt < 32; ++jt) {
        const int j0 = jt * 64;
        __syncthreads();   // prior MFMA2 reads done; K staged at jt==0

        const size_t Qbase = ((size_t)bh * N_ + j0) * DH_;
        for (int c = tid; c < 1024; c += 512) {
            int row = c >> 4, seg = c & 15;
            *(short8*)(ldsQ + row * 264 + seg * 8) =
                *(const short8*)(Qhi + Qbase + (size_t)row * DH_ + seg * 8);
            *(short8*)(ldsQ + row * 264 + 128 + seg * 8) =
                *(const short8*)(Qlo + Qbase + (size_t)row * DH_ + seg * 8);
        }
        const u16* Vg = VT + (size_t)bh * DH_ * N_ + j0;
        for (int c = tid; c < 1024; c += 512) {
            int e = c >> 3, seg = c & 7;
            *(short8*)(ldsV + e * 72 + seg * 8) =
                *(const short8*)(Vg + (size_t)e * N_ + seg * 8);
        }
        if (tid < 64) {
            int j = j0 + tid;
            float l = lrow[(size_t)bh * N_ + j];
            int mj = mask[b * N_ + j];
            int alive = (mj != 0) && (l > 0.f);
            s_il[tid]   = alive ? 1.0f / l : 0.f;
            s_dead[tid] = !alive;
            s_mj[tid]   = mj;
        }
        __syncthreads();

        // MFMA1: S[j(64), i(16 per wave)] — chain matches rowstats
        float4_t accs[4];
#pragma unroll
        for (int mj = 0; mj < 4; ++mj) accs[mj] = (float4_t)(0.f);
#pragma unroll
        for (int t = 0; t < 3; ++t) {
            const int ab = (t == 2) ? 128 : 0;
            const int bb = (t == 1) ? 128 : 0;
#pragma unroll
            for (int kc = 0; kc < 4; ++kc) {
                short8 bfr = *(const short8*)(ldsK + (wave * 16 + l16) * 264 + bb + kc * 32 + quad * 8);
#pragma unroll
                for (int mj = 0; mj < 4; ++mj) {
                    short8 afr = *(const short8*)(ldsQ + (mj * 16 + l16) * 264 + ab + kc * 32 + quad * 8);
                    accs[mj] = __builtin_amdgcn_mfma_f32_16x16x32_bf16(afr, bfr, accs[mj], 0, 0, 0);
                }
            }
        }

        // A = exp(E)*il  (dead row -> 1/N); write A^T to LDS; h==7: fp32 out
#pragma unroll
        for (int mj = 0; mj < 4; ++mj) {
            short4_t pk;
#pragma unroll
            for (int r = 0; r < 4; ++r) {
                int jl = mj * 16 + quad * 4 + r;
                int j = j0 + jl;
                float e = accs[mj][r] + bf2f(APb[(size_t)j * N_ + ig]);
                e = (s_mj[jl] && ion) ? e : -1.0e9f;
                float a = s_dead[jl] ? inv_n : __expf(e) * s_il[jl];
                pk[r] = (short)f2bf(a);
                if (do_aout)
                    aout[((size_t)(b * N_ + j)) * N_ + ig] = a;
            }
            *(short4_t*)(ldsA + (size_t)i_local * 72 + mj * 16 + quad * 4) = pk;
        }
        __syncthreads();

        // MFMA2: y[i(16 per wave), e(128)] += A^T · V
#pragma unroll
        for (int kcj = 0; kcj < 2; ++kcj) {
            short8 afr = *(const short8*)(ldsA + (wave * 16 + l16) * 72 + kcj * 32 + quad * 8);
#pragma unroll
            for (int ne = 0; ne < 8; ++ne) {
                short8 bfr = *(const short8*)(ldsV + (ne * 16 + l16) * 72 + kcj * 32 + quad * 8);
                accy[ne] = __builtin_amdgcn_mfma_f32_16x16x32_bf16(afr, bfr, accy[ne], 0, 0, 0);
            }
        }
    }

#pragma unroll
    for (int ne = 0; ne < 8; ++ne)
#pragma unroll
        for (int r = 0; r < 4; ++r) {
            int irow = wave * 16 + quad * 4 + r;
            int e = ne * 16 + l16;
            yout[((size_t)b * N_ + it * 128 + irow) * D_ + h * DH_ + e] =
                f2bf(accy[ne][r]);
        }
}

// ---------------------------------------------------------------------------
// Kernel 7: out[m,o] = sum_d y[m,d] Wout[o,d]  (bf16 x bf16 -> fp32).
// m97 structure, global_load_lds.
// ---------------------------------------------------------------------------
__global__ __launch_bounds__(256, 4) void outgemm_kernel(
    const u16* __restrict__ A,     // y   [8192][1024] bf16
    const u16* __restrict__ B,     // Wout[1024][1024] bf16 (hi)
    float* __restrict__ C)         // out [8192][1024] fp32
{
    const int nt = blockIdx.x;   // 8
    const int mt = blockIdx.y;   // 64
    const int tid = threadIdx.x, wave = tid >> 6, lane = tid & 63;
    const int quad = lane >> 4, l16 = lane & 15;

    __shared__ __align__(16) u16 sA[128 * 32];
    __shared__ __align__(16) u16 sB[128 * 32];

    const int srow = lane >> 2, scol = (lane & 3) * 8;
    const size_t aoff = ((size_t)(mt * 128) + srow) * 1024 + scol;
    const size_t boff = ((size_t)(nt * 128) + srow) * 1024 + scol;
    const int r0 = wave * 16, r1 = 64 + wave * 16;

    float4_t acc[2][8];
#pragma unroll
    for (int i = 0; i < 2; ++i)
#pragma unroll
        for (int j = 0; j < 8; ++j) acc[i][j] = (float4_t)(0.f);

    for (int kt = 0; kt < 32; ++kt) {
        __syncthreads();
        const int kc0 = kt * 32;
        gl_lds16(A + aoff + (size_t)r0 * 1024 + kc0, &sA[r0 * 32]);
        gl_lds16(A + aoff + (size_t)r1 * 1024 + kc0, &sA[r1 * 32]);
        gl_lds16(B + boff + (size_t)r0 * 1024 + kc0, &sB[r0 * 32]);
        gl_lds16(B + boff + (size_t)r1 * 1024 + kc0, &sB[r1 * 32]);
        __syncthreads();

        short8 afr[2];
#pragma unroll
        for (int mi = 0; mi < 2; ++mi)
            afr[mi] = *(const short8*)(sA + (wave * 32 + mi * 16 + l16) * 32 + quad * 8);
#pragma unroll
        for (int ne = 0; ne < 8; ++ne) {
            short8 bfr = *(const short8*)(sB + (ne * 16 + l16) * 32 + quad * 8);
#pragma unroll
            for (int mi = 0; mi < 2; ++mi)
                acc[mi][ne] = __builtin_amdgcn_mfma_f32_16x16x32_bf16(afr[mi], bfr, acc[mi][ne], 0, 0, 0);
        }
    }

#pragma unroll
    for (int mi = 0; mi < 2; ++mi)
#pragma unroll
        for (int ne = 0; ne < 8; ++ne)
#pragma unroll
            for (int r = 0; r < 4; ++r) {
                int row = mt * 128 + wave * 32 + mi * 16 + quad * 4 + r;
                int col = nt * 128 + ne * 16 + l16;
                C[(size_t)row * D_ + col] = acc[mi][ne][r];
            }
}

// ---------------------------------------------------------------------------
extern "C" void kernel_launch(void* const* d_in, const int* in_sizes, int n_in,
                              void* d_out, int out_size, void* d_ws, size_t ws_size,
                              hipStream_t stream)
{
    const float* x   = (const float*)d_in[0];
    const int*   msk = (const int*)d_in[1];
    const float* Wq  = (const float*)d_in[2];
    const float* Wk  = (const float*)d_in[3];
    const float* Wv  = (const float*)d_in[4];
    const float* Wo  = (const float*)d_in[5];

    float* out  = (float*)d_out;                         // [4,2048,1024] fp32
    float* aout = out + (size_t)BS_ * N_ * D_;           // [4,2048,2048] fp32

    // --- transient split buffers live in d_out (dead before attn/outgemm
    //     fully overwrite these bytes): 44.04 MB of the 100.7 MB output.
    u16* Whi  = (u16*)d_out;                       // 2048*1024
    u16* Wlo  = Whi  + (size_t)2048 * 1024;        // 2048*1024
    u16* Wvhi = Wlo  + (size_t)2048 * 1024;        // 1024*1024
    u16* Xhi  = Wvhi + (size_t)1024 * 1024;        // 8192*1024
    u16* Xlo  = Xhi  + (size_t)8192 * 1024;        // 8192*1024

    // --- workspace (111.4 MB)
    char* w = (char*)d_ws;
    u16* APb = (u16*)w;                       w += (size_t)N_ * N_ * 2;          // 8.39 MB
    const size_t szqk = (size_t)BS_ * H_ * N_ * DH_ * 2;
    u16* Qhi = (u16*)w; w += szqk;
    u16* Qlo = (u16*)w; w += szqk;
    u16* Khi = (u16*)w; w += szqk;
    u16* Klo = (u16*)w; w += szqk;
    u16* VT  = (u16*)w; w += szqk;
    float* lrow = (float*)w;                  w += (size_t)BS_ * H_ * N_ * 4;
    u16* Wohi = (u16*)w;                      w += (size_t)D_ * D_ * 2;
    u16* yb   = (u16*)w;                      w += (size_t)BS_ * N_ * D_ * 2;

    ap_kernel<<<8192, 256, 0, stream>>>((unsigned int*)APb);
    split_kernel<<<12288, 256, 0, stream>>>(x, Wq, Wk, Wv, Wo,
                                            Xhi, Xlo, Whi, Wlo, Wvhi, Wohi);
    qk_gemm<<<dim3(64, 16), 256, 0, stream>>>(Xhi, Xlo, Whi, Wlo,
                                              Qhi, Qlo, Khi, Klo);
    v_gemm<<<dim3(16, 32), 256, 0, stream>>>(Wvhi, Xhi, VT);
    rowstats_kernel<<<dim3(32, 32), 256, 0, stream>>>(Qhi, Qlo, Khi, Klo, APb, msk, lrow);
    attn_kernel<<<dim3(16, 32), 512, 0, stream>>>(Qhi, Qlo, Khi, Klo, VT, APb, msk,
                                                  lrow, yb, aout);
    outgemm_kernel<<<dim3(8, 64), 256, 0, stream>>>(yb, Wohi, out);
}

// Round 5
// 790.731 us; speedup vs baseline: 2.6095x; 1.2818x over previous
//
#include <hip/hip_runtime.h>
#include <math.h>

// Problem constants
#define BS_ 4
#define N_  2048
#define D_  1024
#define H_  8
#define DH_ 128

typedef __attribute__((ext_vector_type(8))) short short8;
typedef __attribute__((ext_vector_type(4))) short short4_t;
typedef __attribute__((ext_vector_type(4))) float float4_t;
typedef unsigned short u16;

__device__ __forceinline__ u16 f2bf(float f) {
    union { float f; unsigned u; } v; v.f = f;
    unsigned r = v.u + 0x7FFFu + ((v.u >> 16) & 1u);   // RNE
    return (u16)(r >> 16);
}
__device__ __forceinline__ float bf2f(u16 h) {
    union { unsigned u; float f; } v; v.u = ((unsigned)h) << 16;
    return v.f;
}
__device__ __forceinline__ void split4(float a, float b, float c, float d,
                                       short4_t* hi, short4_t* lo) {
    u16 h0 = f2bf(a), h1 = f2bf(b), h2 = f2bf(c), h3 = f2bf(d);
    (*hi)[0] = (short)h0; (*hi)[1] = (short)h1; (*hi)[2] = (short)h2; (*hi)[3] = (short)h3;
    (*lo)[0] = (short)f2bf(a - bf2f(h0));
    (*lo)[1] = (short)f2bf(b - bf2f(h1));
    (*lo)[2] = (short)f2bf(c - bf2f(h2));
    (*lo)[3] = (short)f2bf(d - bf2f(h3));
}

// async global->LDS, 16B per lane; LDS dest = wave-uniform base + lane*16.
__device__ __forceinline__ void gl_lds16(const void* g, void* l) {
    __builtin_amdgcn_global_load_lds(
        (const __attribute__((address_space(1))) unsigned int*)g,
        (__attribute__((address_space(3))) unsigned int*)l,
        16, 0, 0);
}

// ---------------------------------------------------------------------------
// Kernel 1: AP table, bf16.  fp32 exp2 instead of double pow (bf16 masks it).
// ---------------------------------------------------------------------------
__global__ void ap_kernel(unsigned int* __restrict__ APb) {
    int idx = blockIdx.x * blockDim.x + threadIdx.x;   // 2,097,152 = 2048*1024
    int p = idx >> 10, u = idx & 1023;
    // 10000^(-2u/1024) = exp2(-u * log2(10000)/512)
    float ex = exp2f(-(float)u * (13.287712379549449f / 512.0f));
    float angle = (float)p * ex;
    unsigned pack = (unsigned)f2bf(sinf(angle)) | ((unsigned)f2bf(cosf(angle)) << 16);
    APb[(size_t)p * (N_ / 2) + u] = pack;   // shorts at p*2048 + 2u
}

// ---------------------------------------------------------------------------
// Kernel 2: fp32 -> bf16 hi/lo pre-split of X, Wq|Wk (cat), Wv (hi), Wout (hi).
// ---------------------------------------------------------------------------
__global__ void split_kernel(const float* __restrict__ x,
                             const float* __restrict__ Wq, const float* __restrict__ Wk,
                             const float* __restrict__ Wv, const float* __restrict__ Wo,
                             u16* __restrict__ Xhi, u16* __restrict__ Xlo,
                             u16* __restrict__ Whi, u16* __restrict__ Wlo,
                             u16* __restrict__ Wvhi, u16* __restrict__ Wohi) {
    int i = blockIdx.x * 256 + threadIdx.x;            // 3,145,728 float4s
    const float* src; u16 *dhi, *dlo; size_t off;
    if (i < 2097152)      { src = x  + 4*(size_t)i;             dhi = Xhi;  dlo = Xlo;  off = 4*(size_t)i; }
    else if (i < 2359296) { size_t j = i - 2097152; src = Wq + 4*j; dhi = Whi; dlo = Wlo; off = 4*j; }
    else if (i < 2621440) { size_t j = i - 2359296; src = Wk + 4*j; dhi = Whi; dlo = Wlo; off = 1048576 + 4*j; }
    else if (i < 2883584) { size_t j = i - 2621440; src = Wv + 4*j; dhi = Wvhi; dlo = nullptr; off = 4*j; }
    else                  { size_t j = i - 2883584; src = Wo + 4*j; dhi = Wohi; dlo = nullptr; off = 4*j; }
    float4 v = *(const float4*)src;
    short4_t hi, lo;
    split4(v.x, v.y, v.z, v.w, &hi, &lo);
    *(short4_t*)(dhi + off) = hi;
    if (dlo) *(short4_t*)(dlo + off) = lo;
}

// ---------------------------------------------------------------------------
// Kernel 3: Q,K projections.  3-term bf16 split, m97 structure (unchanged).
// ---------------------------------------------------------------------------
__global__ __launch_bounds__(256, 4) void qk_gemm(
    const u16* __restrict__ Xhi, const u16* __restrict__ Xlo,
    const u16* __restrict__ Whi, const u16* __restrict__ Wlo,
    u16* __restrict__ Qhi, u16* __restrict__ Qlo,
    u16* __restrict__ Khi, u16* __restrict__ Klo)
{
    const int mt = blockIdx.x;   // 64
    const int nt = blockIdx.y;   // 16
    const int tid = threadIdx.x, wave = tid >> 6, lane = tid & 63;
    const int quad = lane >> 4, l16 = lane & 15;

    __shared__ __align__(16) u16 sA[2][128 * 32];
    __shared__ __align__(16) u16 sB[2][128 * 32];

    const int srow = lane >> 2;
    const int scol = (lane & 3) * 8;
    const size_t aoff = ((size_t)(mt * 128) + srow) * 1024 + scol;
    const size_t boff = ((size_t)(nt * 128) + srow) * 1024 + scol;
    const int r0 = wave * 16, r1 = 64 + wave * 16;

    float4_t acc[2][8];
#pragma unroll
    for (int i = 0; i < 2; ++i)
#pragma unroll
        for (int j = 0; j < 8; ++j) acc[i][j] = (float4_t)(0.f);

    for (int kt = 0; kt < 32; ++kt) {
        __syncthreads();
        const int kc0 = kt * 32;
        gl_lds16(Xhi + aoff + (size_t)r0 * 1024 + kc0, &sA[0][r0 * 32]);
        gl_lds16(Xhi + aoff + (size_t)r1 * 1024 + kc0, &sA[0][r1 * 32]);
        gl_lds16(Xlo + aoff + (size_t)r0 * 1024 + kc0, &sA[1][r0 * 32]);
        gl_lds16(Xlo + aoff + (size_t)r1 * 1024 + kc0, &sA[1][r1 * 32]);
        gl_lds16(Whi + boff + (size_t)r0 * 1024 + kc0, &sB[0][r0 * 32]);
        gl_lds16(Whi + boff + (size_t)r1 * 1024 + kc0, &sB[0][r1 * 32]);
        gl_lds16(Wlo + boff + (size_t)r0 * 1024 + kc0, &sB[1][r0 * 32]);
        gl_lds16(Wlo + boff + (size_t)r1 * 1024 + kc0, &sB[1][r1 * 32]);
        __syncthreads();

#pragma unroll
        for (int t = 0; t < 3; ++t) {
            const u16* As = sA[t == 2 ? 1 : 0];
            const u16* Bs = sB[t == 1 ? 1 : 0];
            short8 afr[2];
#pragma unroll
            for (int mi = 0; mi < 2; ++mi)
                afr[mi] = *(const short8*)(As + (wave * 32 + mi * 16 + l16) * 32 + quad * 8);
#pragma unroll
            for (int ne = 0; ne < 8; ++ne) {
                short8 bfr = *(const short8*)(Bs + (ne * 16 + l16) * 32 + quad * 8);
#pragma unroll
                for (int mi = 0; mi < 2; ++mi)
                    acc[mi][ne] = __builtin_amdgcn_mfma_f32_16x16x32_bf16(afr[mi], bfr, acc[mi][ne], 0, 0, 0);
            }
        }
    }

    const int b = mt >> 4, q0 = (mt & 15) * 128;
    const bool isQ = (nt < 8);
    u16* Hi = isQ ? Qhi : Khi;
    u16* Lo = isQ ? Qlo : Klo;
    const int h = isQ ? nt : nt - 8;
    const size_t base = (size_t)(b * 8 + h) * N_ * DH_;
#pragma unroll
    for (int mi = 0; mi < 2; ++mi)
#pragma unroll
        for (int ne = 0; ne < 8; ++ne)
#pragma unroll
            for (int r = 0; r < 4; ++r) {
                int q = q0 + wave * 32 + mi * 16 + quad * 4 + r;
                int e = ne * 16 + l16;
                float v = acc[mi][ne][r];
                u16 hv = f2bf(v);
                Hi[base + (size_t)q * DH_ + e] = hv;
                Lo[base + (size_t)q * DH_ + e] = f2bf(v - bf2f(hv));
            }
}

// ---------------------------------------------------------------------------
// Kernel 4: V^T[bh][e][q]  (1-term bf16, unchanged).
// ---------------------------------------------------------------------------
__global__ __launch_bounds__(256, 4) void v_gemm(
    const u16* __restrict__ Wvhi, const u16* __restrict__ Xhi,
    u16* __restrict__ VT)
{
    const int qt = blockIdx.x;   // 16
    const int bh = blockIdx.y;   // 32
    const int b = bh >> 3, h = bh & 7;
    const int tid = threadIdx.x, wave = tid >> 6, lane = tid & 63;
    const int quad = lane >> 4, l16 = lane & 15;

    __shared__ __align__(16) u16 sA[128 * 32];
    __shared__ __align__(16) u16 sB[128 * 32];

    const int srow = lane >> 2, scol = (lane & 3) * 8;
    const size_t aoff = ((size_t)(h * 128) + srow) * 1024 + scol;
    const size_t boff = ((size_t)(b * N_ + qt * 128) + srow) * 1024 + scol;
    const int r0 = wave * 16, r1 = 64 + wave * 16;

    float4_t acc[2][8];
#pragma unroll
    for (int i = 0; i < 2; ++i)
#pragma unroll
        for (int j = 0; j < 8; ++j) acc[i][j] = (float4_t)(0.f);

    for (int kt = 0; kt < 32; ++kt) {
        __syncthreads();
        const int kc0 = kt * 32;
        gl_lds16(Wvhi + aoff + (size_t)r0 * 1024 + kc0, &sA[r0 * 32]);
        gl_lds16(Wvhi + aoff + (size_t)r1 * 1024 + kc0, &sA[r1 * 32]);
        gl_lds16(Xhi  + boff + (size_t)r0 * 1024 + kc0, &sB[r0 * 32]);
        gl_lds16(Xhi  + boff + (size_t)r1 * 1024 + kc0, &sB[r1 * 32]);
        __syncthreads();

        short8 afr[2];
#pragma unroll
        for (int mi = 0; mi < 2; ++mi)
            afr[mi] = *(const short8*)(sA + (wave * 32 + mi * 16 + l16) * 32 + quad * 8);
#pragma unroll
        for (int ne = 0; ne < 8; ++ne) {
            short8 bfr = *(const short8*)(sB + (ne * 16 + l16) * 32 + quad * 8);
#pragma unroll
            for (int mi = 0; mi < 2; ++mi)
                acc[mi][ne] = __builtin_amdgcn_mfma_f32_16x16x32_bf16(afr[mi], bfr, acc[mi][ne], 0, 0, 0);
        }
    }

    u16* Cg = VT + (size_t)bh * DH_ * N_;
#pragma unroll
    for (int mi = 0; mi < 2; ++mi)
#pragma unroll
        for (int ne = 0; ne < 8; ++ne)
#pragma unroll
            for (int r = 0; r < 4; ++r) {
                int e = wave * 32 + mi * 16 + quad * 4 + r;
                int q = qt * 128 + ne * 16 + l16;
                Cg[(size_t)e * N_ + q] = f2bf(acc[mi][ne][r]);
            }
}

// ---------------------------------------------------------------------------
// Kernel 5 (pass A): l_j = sum_k exp(E[j,k]).  512 thr / 8 waves.
// Q (64 j) resident; K-tiles of 64 + AP tile STREAMED with reg-prefetch
// double-buffering; ONE barrier per iter.  Wave w: j-sub (w&3)*16, k-half w>>2.
// MFMA chain (t-major, kc-minor, 12 steps) bitwise-matches attn MFMA1.
// ---------------------------------------------------------------------------
__global__ __launch_bounds__(512, 2) void rowstats_kernel(
    const u16* __restrict__ Qhi, const u16* __restrict__ Qlo,
    const u16* __restrict__ Khi, const u16* __restrict__ Klo,
    const u16* __restrict__ APb,
    const int* __restrict__ mask,
    float* __restrict__ lrow)
{
    const int jt = blockIdx.x;    // 32 j-tiles of 64
    const int bh = blockIdx.y;    // 32
    const int b = bh >> 3;
    const int tid = threadIdx.x, wave = tid >> 6, lane = tid & 63;
    const int quad = lane >> 4, l16 = lane & 15;
    const int jsub = (wave & 3) * 16, khalf = wave >> 2;

    __shared__ __align__(16) u16 ldsQ[64 * 264];       // resident, split
    __shared__ __align__(16) u16 ldsK[2][64 * 264];    // streamed, split
    __shared__ __align__(16) u16 ldsAP[2][64 * 72];    // streamed
    __shared__ int   s_mk[2][64];
    __shared__ float psum[64 * 2];

    // resident Q + buf0
    const size_t Qbase = ((size_t)bh * N_ + (size_t)jt * 64) * DH_;
    for (int c = tid; c < 2048; c += 512) {
        int row = c >> 5, half = (c >> 4) & 1, seg = c & 15;
        *(short8*)(ldsQ + row * 264 + half * 128 + seg * 8) =
            *(const short8*)((half ? Qlo : Qhi) + Qbase + (size_t)row * DH_ + seg * 8);
    }
    {
        const size_t Kb = ((size_t)bh * N_) * DH_;
        for (int c = tid; c < 2048; c += 512) {
            int row = c >> 5, half = (c >> 4) & 1, seg = c & 15;
            *(short8*)(ldsK[0] + row * 264 + half * 128 + seg * 8) =
                *(const short8*)((half ? Klo : Khi) + Kb + (size_t)row * DH_ + seg * 8);
        }
        int row = tid >> 3, seg = tid & 7;
        *(short8*)(ldsAP[0] + row * 72 + seg * 8) =
            *(const short8*)(APb + (size_t)(jt * 64 + row) * N_ + seg * 8);
        if (tid < 64) s_mk[0][tid] = mask[b * N_ + tid];
    }

    float p[4] = {0.f, 0.f, 0.f, 0.f};
    int mj_on[4];
#pragma unroll
    for (int r = 0; r < 4; ++r)
        mj_on[r] = mask[b * N_ + jt * 64 + jsub + quad * 4 + r];

    __syncthreads();

    for (int kt = 0; kt < 32; ++kt) {
        const int cur = kt & 1, nxt = cur ^ 1;
        short8 rK[4], rAP;
        int rmk = 0;
        if (kt < 31) {
            const size_t Kb2 = ((size_t)bh * N_ + (size_t)(kt + 1) * 64) * DH_;
#pragma unroll
            for (int i = 0; i < 4; ++i) {
                int c = tid + i * 512;
                int row = c >> 5, half = (c >> 4) & 1, seg = c & 15;
                rK[i] = *(const short8*)((half ? Klo : Khi) + Kb2 + (size_t)row * DH_ + seg * 8);
            }
            int row = tid >> 3, seg = tid & 7;
            rAP = *(const short8*)(APb + (size_t)(jt * 64 + row) * N_ + (kt + 1) * 64 + seg * 8);
            if (tid < 64) rmk = mask[b * N_ + (kt + 1) * 64 + tid];
        }

        // MFMA: S[16 j][32 k per wave]
        float4_t acc[2];
        acc[0] = (float4_t)(0.f); acc[1] = (float4_t)(0.f);
#pragma unroll
        for (int t = 0; t < 3; ++t) {
            const int ab = (t == 2) ? 128 : 0;
            const int bb = (t == 1) ? 128 : 0;
#pragma unroll
            for (int kc = 0; kc < 4; ++kc) {
                short8 afr = *(const short8*)(ldsQ + (jsub + l16) * 264 + ab + kc * 32 + quad * 8);
#pragma unroll
                for (int nk = 0; nk < 2; ++nk) {
                    short8 bfr = *(const short8*)(ldsK[cur] + (khalf * 32 + nk * 16 + l16) * 264 + bb + kc * 32 + quad * 8);
                    acc[nk] = __builtin_amdgcn_mfma_f32_16x16x32_bf16(afr, bfr, acc[nk], 0, 0, 0);
                }
            }
        }

#pragma unroll
        for (int r = 0; r < 4; ++r) {
            int jl = jsub + quad * 4 + r;
            int on = mj_on[r];
            float s = 0.f;
#pragma unroll
            for (int nk = 0; nk < 2; ++nk) {
                int kk = khalf * 32 + nk * 16 + l16;
                float e = acc[nk][r] + bf2f(ldsAP[cur][jl * 72 + kk]);
                e = (on && s_mk[cur][kk]) ? e : -1.0e9f;
                s += __expf(e);
            }
            p[r] += s;
        }

        if (kt < 31) {
#pragma unroll
            for (int i = 0; i < 4; ++i) {
                int c = tid + i * 512;
                int row = c >> 5, half = (c >> 4) & 1, seg = c & 15;
                *(short8*)(ldsK[nxt] + row * 264 + half * 128 + seg * 8) = rK[i];
            }
            int row = tid >> 3, seg = tid & 7;
            *(short8*)(ldsAP[nxt] + row * 72 + seg * 8) = rAP;
            if (tid < 64) s_mk[nxt][tid] = rmk;
        }
        __syncthreads();
    }

    // reduce over l16 lanes, then over the two k-half waves
#pragma unroll
    for (int r = 0; r < 4; ++r) {
        float s = p[r];
        for (int off = 1; off < 16; off <<= 1)
            s += __shfl_xor(s, off, 64);
        if (l16 == 0)
            psum[(jsub + quad * 4 + r) * 2 + khalf] = s;
    }
    __syncthreads();
    if (tid < 64)
        lrow[(size_t)bh * N_ + jt * 64 + tid] = psum[tid * 2] + psum[tid * 2 + 1];
}

// ---------------------------------------------------------------------------
// Kernel 6 (pass B): y[i,e] = sum_j A[j,i] V[j,e], A = exp(E)/l_j.
// 512 thr / 8 waves.  K_i (128, split) resident; j-tiles of 32: Q/V/AP/stats
// streamed with reg-prefetch double-buffering; 2 barriers per iter.
// MFMA1 chain matches rowstats.  h==7 stores A (fp32) to d_out.
// ---------------------------------------------------------------------------
__global__ __launch_bounds__(512, 2) void attn_kernel(
    const u16* __restrict__ Qhi, const u16* __restrict__ Qlo,
    const u16* __restrict__ Khi, const u16* __restrict__ Klo,
    const u16* __restrict__ VT,
    const u16* __restrict__ APb,
    const int* __restrict__ mask,
    const float* __restrict__ lrow,
    u16* __restrict__ yout,               // [BS,N,D] bf16 (ws)
    float* __restrict__ aout)             // [BS,N,N] fp32 (d_out tail)
{
    const int it = blockIdx.x;   // 16 i-tiles (keys)
    const int bh = blockIdx.y;   // 32
    const int b = bh >> 3, h = bh & 7;
    const int tid = threadIdx.x, wave = tid >> 6, lane = tid & 63;  // 8 waves
    const int quad = lane >> 4, l16 = lane & 15;

    __shared__ __align__(16) u16 ldsK[128 * 264];      // K_i split, resident (67.6 KB)
    __shared__ __align__(16) u16 ldsQ[2][32 * 264];    // Q_j split, dbuf     (33.8 KB)
    __shared__ __align__(16) u16 ldsV[2][128 * 40];    // V^T [e][j], dbuf    (20.5 KB)
    __shared__ __align__(16) u16 ldsAP[2][32 * 136];   // AP [j][i], dbuf     (17.4 KB)
    __shared__ __align__(16) u16 ldsA[128 * 40];       // A^T [i][j]          (10.2 KB)
    __shared__ float s_il[2][32];
    __shared__ int   s_dead[2][32];
    __shared__ int   s_mj[2][32];

    // resident K
    const size_t Kbase = ((size_t)bh * N_ + (size_t)it * 128) * DH_;
    for (int c = tid; c < 4096; c += 512) {
        int row = c >> 5, half = (c >> 4) & 1, seg = c & 15;
        *(short8*)(ldsK + row * 264 + half * 128 + seg * 8) =
            *(const short8*)((half ? Klo : Khi) + Kbase + (size_t)row * DH_ + seg * 8);
    }
    // buf0 (jt = 0)
    {
        const size_t Qb0 = ((size_t)bh * N_) * DH_;
        for (int c = tid; c < 1024; c += 512) {
            int row = c >> 5, half = (c >> 4) & 1, seg = c & 15;
            *(short8*)(ldsQ[0] + row * 264 + half * 128 + seg * 8) =
                *(const short8*)((half ? Qlo : Qhi) + Qb0 + (size_t)row * DH_ + seg * 8);
        }
        { int e = tid >> 2, seg = tid & 3;
          *(short8*)(ldsV[0] + e * 40 + seg * 8) =
              *(const short8*)(VT + (size_t)bh * DH_ * N_ + (size_t)e * N_ + seg * 8); }
        { int row = tid >> 4, seg = tid & 15;
          *(short8*)(ldsAP[0] + row * 136 + seg * 8) =
              *(const short8*)(APb + (size_t)row * N_ + it * 128 + seg * 8); }
        if (tid < 32) {
            float l = lrow[(size_t)bh * N_ + tid];
            int mj = mask[b * N_ + tid];
            int alive = (mj != 0) && (l > 0.f);
            s_il[0][tid] = alive ? 1.0f / l : 0.f;
            s_dead[0][tid] = !alive;
            s_mj[0][tid] = mj;
        }
    }

    const int i_local = wave * 16 + l16;
    const int ig = it * 128 + i_local;
    const int ion = mask[b * N_ + ig];

    float4_t accy[8];
#pragma unroll
    for (int ne = 0; ne < 8; ++ne) accy[ne] = (float4_t)(0.f);

    const bool do_aout = (h == 7);
    const float inv_n = 1.0f / (float)N_;

    __syncthreads();

    for (int jt = 0; jt < 64; ++jt) {
        const int cur = jt & 1, nxt = cur ^ 1;
        const int j0 = jt * 32;

        // prefetch next j-tile into registers (hidden under MFMA1+epi+MFMA2)
        short8 rQ[2], rV, rAP;
        float r_il = 0.f; int r_dead = 0, r_mj = 0;
        if (jt < 63) {
            const int j0n = j0 + 32;
            const size_t Qb2 = ((size_t)bh * N_ + j0n) * DH_;
#pragma unroll
            for (int i = 0; i < 2; ++i) {
                int c = tid + i * 512;
                int row = c >> 5, half = (c >> 4) & 1, seg = c & 15;
                rQ[i] = *(const short8*)((half ? Qlo : Qhi) + Qb2 + (size_t)row * DH_ + seg * 8);
            }
            { int e = tid >> 2, seg = tid & 3;
              rV = *(const short8*)(VT + (size_t)bh * DH_ * N_ + (size_t)e * N_ + j0n + seg * 8); }
            { int row = tid >> 4, seg = tid & 15;
              rAP = *(const short8*)(APb + (size_t)(j0n + row) * N_ + it * 128 + seg * 8); }
            if (tid < 32) {
                float l = lrow[(size_t)bh * N_ + j0n + tid];
                r_mj = mask[b * N_ + j0n + tid];
                int alive = (r_mj != 0) && (l > 0.f);
                r_il = alive ? 1.0f / l : 0.f;
                r_dead = !alive;
            }
        }

        // MFMA1: S[j(32), i(16 per wave)] — chain matches rowstats
        float4_t accs[2];
        accs[0] = (float4_t)(0.f); accs[1] = (float4_t)(0.f);
#pragma unroll
        for (int t = 0; t < 3; ++t) {
            const int ab = (t == 2) ? 128 : 0;
            const int bb = (t == 1) ? 128 : 0;
#pragma unroll
            for (int kc = 0; kc < 4; ++kc) {
                short8 bfr = *(const short8*)(ldsK + (wave * 16 + l16) * 264 + bb + kc * 32 + quad * 8);
#pragma unroll
                for (int mj = 0; mj < 2; ++mj) {
                    short8 afr = *(const short8*)(ldsQ[cur] + (mj * 16 + l16) * 264 + ab + kc * 32 + quad * 8);
                    accs[mj] = __builtin_amdgcn_mfma_f32_16x16x32_bf16(afr, bfr, accs[mj], 0, 0, 0);
                }
            }
        }

        // A = exp(E)*il (dead row -> 1/N); write A^T to LDS; h==7: fp32 out
#pragma unroll
        for (int mj = 0; mj < 2; ++mj) {
            short4_t pk;
#pragma unroll
            for (int r = 0; r < 4; ++r) {
                int jl = mj * 16 + quad * 4 + r;
                float e = accs[mj][r] + bf2f(ldsAP[cur][jl * 136 + i_local]);
                e = (s_mj[cur][jl] && ion) ? e : -1.0e9f;
                float a = s_dead[cur][jl] ? inv_n : __expf(e) * s_il[cur][jl];
                pk[r] = (short)f2bf(a);
                if (do_aout)
                    aout[((size_t)(b * N_ + j0 + jl)) * N_ + ig] = a;
            }
            *(short4_t*)(ldsA + (size_t)i_local * 40 + mj * 16 + quad * 4) = pk;
        }
        __syncthreads();   // B1: ldsA ready; reads of ldsQ/ldsAP[cur] done

        // MFMA2: y[i(16 per wave), e(128)] += A^T · V   (k = 32)
        {
            short8 afr = *(const short8*)(ldsA + (wave * 16 + l16) * 40 + quad * 8);
#pragma unroll
            for (int ne = 0; ne < 8; ++ne) {
                short8 bfr = *(const short8*)(ldsV[cur] + (ne * 16 + l16) * 40 + quad * 8);
                accy[ne] = __builtin_amdgcn_mfma_f32_16x16x32_bf16(afr, bfr, accy[ne], 0, 0, 0);
            }
        }

        if (jt < 63) {
#pragma unroll
            for (int i = 0; i < 2; ++i) {
                int c = tid + i * 512;
                int row = c >> 5, half = (c >> 4) & 1, seg = c & 15;
                *(short8*)(ldsQ[nxt] + row * 264 + half * 128 + seg * 8) = rQ[i];
            }
            { int e = tid >> 2, seg = tid & 3;
              *(short8*)(ldsV[nxt] + e * 40 + seg * 8) = rV; }
            { int row = tid >> 4, seg = tid & 15;
              *(short8*)(ldsAP[nxt] + row * 136 + seg * 8) = rAP; }
            if (tid < 32) {
                s_il[nxt][tid] = r_il;
                s_dead[nxt][tid] = r_dead;
                s_mj[nxt][tid] = r_mj;
            }
        }
        __syncthreads();   // B2: buf[nxt] ready; ldsA reads done
    }

#pragma unroll
    for (int ne = 0; ne < 8; ++ne)
#pragma unroll
        for (int r = 0; r < 4; ++r) {
            int irow = wave * 16 + quad * 4 + r;
            int e = ne * 16 + l16;
            yout[((size_t)b * N_ + it * 128 + irow) * D_ + h * DH_ + e] =
                f2bf(accy[ne][r]);
        }
}

// ---------------------------------------------------------------------------
// Kernel 7: out[m,o] = sum_d y[m,d] Wout[o,d]  (unchanged).
// ---------------------------------------------------------------------------
__global__ __launch_bounds__(256, 4) void outgemm_kernel(
    const u16* __restrict__ A,     // y   [8192][1024] bf16
    const u16* __restrict__ B,     // Wout[1024][1024] bf16 (hi)
    float* __restrict__ C)         // out [8192][1024] fp32
{
    const int nt = blockIdx.x;   // 8
    const int mt = blockIdx.y;   // 64
    const int tid = threadIdx.x, wave = tid >> 6, lane = tid & 63;
    const int quad = lane >> 4, l16 = lane & 15;

    __shared__ __align__(16) u16 sA[128 * 32];
    __shared__ __align__(16) u16 sB[128 * 32];

    const int srow = lane >> 2, scol = (lane & 3) * 8;
    const size_t aoff = ((size_t)(mt * 128) + srow) * 1024 + scol;
    const size_t boff = ((size_t)(nt * 128) + srow) * 1024 + scol;
    const int r0 = wave * 16, r1 = 64 + wave * 16;

    float4_t acc[2][8];
#pragma unroll
    for (int i = 0; i < 2; ++i)
#pragma unroll
        for (int j = 0; j < 8; ++j) acc[i][j] = (float4_t)(0.f);

    for (int kt = 0; kt < 32; ++kt) {
        __syncthreads();
        const int kc0 = kt * 32;
        gl_lds16(A + aoff + (size_t)r0 * 1024 + kc0, &sA[r0 * 32]);
        gl_lds16(A + aoff + (size_t)r1 * 1024 + kc0, &sA[r1 * 32]);
        gl_lds16(B + boff + (size_t)r0 * 1024 + kc0, &sB[r0 * 32]);
        gl_lds16(B + boff + (size_t)r1 * 1024 + kc0, &sB[r1 * 32]);
        __syncthreads();

        short8 afr[2];
#pragma unroll
        for (int mi = 0; mi < 2; ++mi)
            afr[mi] = *(const short8*)(sA + (wave * 32 + mi * 16 + l16) * 32 + quad * 8);
#pragma unroll
        for (int ne = 0; ne < 8; ++ne) {
            short8 bfr = *(const short8*)(sB + (ne * 16 + l16) * 32 + quad * 8);
#pragma unroll
            for (int mi = 0; mi < 2; ++mi)
                acc[mi][ne] = __builtin_amdgcn_mfma_f32_16x16x32_bf16(afr[mi], bfr, acc[mi][ne], 0, 0, 0);
        }
    }

#pragma unroll
    for (int mi = 0; mi < 2; ++mi)
#pragma unroll
        for (int ne = 0; ne < 8; ++ne)
#pragma unroll
            for (int r = 0; r < 4; ++r) {
                int row = mt * 128 + wave * 32 + mi * 16 + quad * 4 + r;
                int col = nt * 128 + ne * 16 + l16;
                C[(size_t)row * D_ + col] = acc[mi][ne][r];
            }
}

// ---------------------------------------------------------------------------
extern "C" void kernel_launch(void* const* d_in, const int* in_sizes, int n_in,
                              void* d_out, int out_size, void* d_ws, size_t ws_size,
                              hipStream_t stream)
{
    const float* x   = (const float*)d_in[0];
    const int*   msk = (const int*)d_in[1];
    const float* Wq  = (const float*)d_in[2];
    const float* Wk  = (const float*)d_in[3];
    const float* Wv  = (const float*)d_in[4];
    const float* Wo  = (const float*)d_in[5];

    float* out  = (float*)d_out;                         // [4,2048,1024] fp32
    float* aout = out + (size_t)BS_ * N_ * D_;           // [4,2048,2048] fp32

    // transient split buffers in d_out (dead before attn/outgemm overwrite)
    u16* Whi  = (u16*)d_out;                       // 2048*1024
    u16* Wlo  = Whi  + (size_t)2048 * 1024;        // 2048*1024
    u16* Wvhi = Wlo  + (size_t)2048 * 1024;        // 1024*1024
    u16* Xhi  = Wvhi + (size_t)1024 * 1024;        // 8192*1024
    u16* Xlo  = Xhi  + (size_t)8192 * 1024;        // 8192*1024

    // workspace (111.4 MB)
    char* w = (char*)d_ws;
    u16* APb = (u16*)w;                       w += (size_t)N_ * N_ * 2;
    const size_t szqk = (size_t)BS_ * H_ * N_ * DH_ * 2;
    u16* Qhi = (u16*)w; w += szqk;
    u16* Qlo = (u16*)w; w += szqk;
    u16* Khi = (u16*)w; w += szqk;
    u16* Klo = (u16*)w; w += szqk;
    u16* VT  = (u16*)w; w += szqk;
    float* lrow = (float*)w;                  w += (size_t)BS_ * H_ * N_ * 4;
    u16* Wohi = (u16*)w;                      w += (size_t)D_ * D_ * 2;
    u16* yb   = (u16*)w;                      w += (size_t)BS_ * N_ * D_ * 2;

    ap_kernel<<<8192, 256, 0, stream>>>((unsigned int*)APb);
    split_kernel<<<12288, 256, 0, stream>>>(x, Wq, Wk, Wv, Wo,
                                            Xhi, Xlo, Whi, Wlo, Wvhi, Wohi);
    qk_gemm<<<dim3(64, 16), 256, 0, stream>>>(Xhi, Xlo, Whi, Wlo,
                                              Qhi, Qlo, Khi, Klo);
    v_gemm<<<dim3(16, 32), 256, 0, stream>>>(Wvhi, Xhi, VT);
    rowstats_kernel<<<dim3(32, 32), 512, 0, stream>>>(Qhi, Qlo, Khi, Klo, APb, msk, lrow);
    attn_kernel<<<dim3(16, 32), 512, 0, stream>>>(Qhi, Qlo, Khi, Klo, VT, APb, msk,
                                                  lrow, yb, aout);
    outgemm_kernel<<<dim3(8, 64), 256, 0, stream>>>(yb, Wohi, out);
}